// Round 6
// baseline (316.441 us; speedup 1.0000x reference)
//
#include <hip/hip_runtime.h>
#include <hip/hip_bf16.h>

// MACE-like GNN on MI355X — MFMA + prep-baked weights.
// B=32, N=128, F=64, N_RBF=8, H_R=64, L=2.
// Round 6: coalesced wT4 tail layout ([ff4][g][4]) + 6 blocks/CU occupancy.

#define NN 128
#define BB 32
#define FF 64

using f32x4  = __attribute__((ext_vector_type(4))) float;
using short8 = __attribute__((ext_vector_type(8))) short;

__device__ __forceinline__ unsigned short f2bf(float x) {
    unsigned int u = __float_as_uint(x);
    u += 0x7fff + ((u >> 16) & 1);          // RNE
    return (unsigned short)(u >> 16);
}
__device__ __forceinline__ unsigned short f2bf_fast(float x) {
    return (unsigned short)((__float_as_uint(x) + 0x8000u) >> 16);
}

// -------------------- prep: bake weights into fast layouts -----------------
// w2frag: [layer][wave][nt][ks][lane][e]  bf16, scaled by 1/127
// wT4:    [layer][m(0=ws,1=wv)][ff4][g][4]  f32; element (.,c) = w[(ff4*4+c)*64+g]
__global__ __launch_bounds__(256) void prep_kernel(
    const float* __restrict__ w2,    // [2][64][192]
    const float* __restrict__ ws,    // [2][64][64]
    const float* __restrict__ wv,    // [2][64][64]
    short* __restrict__ w2frag,      // [2][4][3][2][64][8] = 24576 shorts
    float* __restrict__ wT4)         // [2][2][16][64][4]   = 16384 floats
{
    const int tid = blockIdx.x * 256 + threadIdx.x;
    const int NFRAG = 24576;
    if (tid < NFRAG) {
        const int e  = tid & 7;
        const int l  = (tid >> 3) & 63;
        const int ks = (tid >> 9) & 1;
        const int q  = tid >> 10;          // layer*12 + wave*3 + nt
        const int nt = q % 3;
        const int wv_ = (q / 3) & 3;
        const int layer = q / 12;
        const int col = nt * 64 + wv_ * 16 + (l & 15);
        const int hb  = ks * 32 + (l >> 4) * 8 + e;
        const float val = w2[layer * 64 * 192 + hb * 192 + col] * (1.0f / 127.0f);
        w2frag[tid] = (short)f2bf(val);
    }
    const int tid2 = tid - NFRAG;
    if (tid2 >= 0 && tid2 < 16384) {
        const int c   = tid2 & 3;
        const int g   = (tid2 >> 2) & 63;
        const int ff4 = (tid2 >> 8) & 15;
        const int m   = (tid2 >> 12) & 1;
        const int layer = tid2 >> 13;
        const float* src = (m == 0 ? ws : wv) + layer * 4096;
        wT4[tid2] = src[(ff4 * 4 + c) * 64 + g];
    }
}

// -------------------- init: s = embed[species] + glob @ glob_w -------------
__global__ __launch_bounds__(256) void init_kernel(
    const int* __restrict__ species, const float* __restrict__ glob,
    const float* __restrict__ embed, const float* __restrict__ glob_w,
    float* __restrict__ s)
{
    const int node = blockIdx.x * 4 + (threadIdx.x >> 6);   // b*128 + n
    const int b = node >> 7;
    const int f = threadIdx.x & 63;
    const int sp = species[node];
    float acc = embed[sp * FF + f];
#pragma unroll
    for (int k = 0; k < 16; ++k)
        acc = fmaf(glob[b * 16 + k], glob_w[k * FF + f], acc);
    s[node * FF + f] = acc;
}

// -------------------- fused message+agg+update (+readout for LAYER==1) ----
// grid (128 receivers, 32 batch), block 256 = 4 waves.
// wave w owns channels f in [16w, 16w+16).
template<int LAYER>
__global__ __launch_bounds__(256, 6) void msg_kernel(
    const float* __restrict__ pos,     // [B][N][3]
    const float* __restrict__ s_in,    // [B][N][F]
    const float* __restrict__ v_in,    // [B][N][F][4]  (unused when LAYER==0)
    const float* __restrict__ w1,      // [8][64]
    const float* __restrict__ b1,      // [64]
    const short* __restrict__ w2frag,  // [4][3][2][64][8] bf16 (layer slice)
    const float* __restrict__ wT4,     // [2][16][64][4] (ws,wv; layer slice)
    const float* __restrict__ wout,    // [64]
    const float* __restrict__ scale,   // [1]
    float* __restrict__ s_out,         // LAYER==0 only
    float* __restrict__ v_out,         // LAYER==0 only, [B][N][F][4]
    float* __restrict__ out)           // LAYER==1 only
{
    __shared__ unsigned short hid_lds[NN * 64];   // 16 KB, XOR-swizzled rows
    __shared__ float4 unit_lds[NN];
    __shared__ float4 phiA[NN], phiB[NN];
    __shared__ float4 agg4[4][16];

    const int i = blockIdx.x;
    const int b = blockIdx.y;
    const int t = threadIdx.x;
    const int w = t >> 6;          // wave
    const int l = t & 63;          // lane
    const int node = b * NN + i;
    const float* pb = pos + b * NN * 3;

    // ---- B fragments: pre-baked, 6 coalesced 16B loads (hide under A1/A2) --
    short8 bfrag[3][2];
    {
        const short8* wf = (const short8*)w2frag;
#pragma unroll
        for (int nt = 0; nt < 3; ++nt)
#pragma unroll
            for (int ks = 0; ks < 2; ++ks)
                bfrag[nt][ks] = wf[((w * 3 + nt) * 2 + ks) * 64 + l];
    }

    // ---- phase A1: per-edge distance, unit vector, and RBF (once per j) ---
    if (t < NN) {
        const int j = t;
        const float dx = pb[i * 3 + 0] - pb[j * 3 + 0];
        const float dy = pb[i * 3 + 1] - pb[j * 3 + 1];
        const float dz = pb[i * 3 + 2] - pb[j * 3 + 2];
        const float d2 = fmaf(dx, dx, fmaf(dy, dy, fmaf(dz, dz, 1e-12f)));
        const float inv = __builtin_amdgcn_rsqf(d2);
        const float dd = d2 * inv;
        unit_lds[j] = make_float4(dx * inv, dy * inv, dz * inv, 0.0f);
        float ph[8];
#pragma unroll
        for (int r = 0; r < 8; ++r) {
            const float td = dd - (float)r * (5.0f / 7.0f);
            ph[r] = __expf(td * td * -1.28f);   // 1/(2*0.625^2) = 1.28
        }
        phiA[j] = make_float4(ph[0], ph[1], ph[2], ph[3]);
        phiB[j] = make_float4(ph[4], ph[5], ph[6], ph[7]);
    }
    __syncthreads();

    // ---- phase A2: hid[j][h] = silu(phi(d_j) @ W1 + b1), bf16 -> LDS ----
    {
        const int h0 = (t & 7) * 8;    // h-chunk (8 units)
        const int jb = t >> 3;         // 0..31
        float w1r[8][8];
#pragma unroll
        for (int r = 0; r < 8; ++r) {
            const float4 a0 = *(const float4*)(w1 + r * 64 + h0);
            const float4 a1 = *(const float4*)(w1 + r * 64 + h0 + 4);
            w1r[r][0] = a0.x; w1r[r][1] = a0.y; w1r[r][2] = a0.z; w1r[r][3] = a0.w;
            w1r[r][4] = a1.x; w1r[r][5] = a1.y; w1r[r][6] = a1.z; w1r[r][7] = a1.w;
        }
        float b1r[8];
        {
            const float4 c0 = *(const float4*)(b1 + h0);
            const float4 c1 = *(const float4*)(b1 + h0 + 4);
            b1r[0] = c0.x; b1r[1] = c0.y; b1r[2] = c0.z; b1r[3] = c0.w;
            b1r[4] = c1.x; b1r[5] = c1.y; b1r[6] = c1.z; b1r[7] = c1.w;
        }
#pragma unroll
        for (int it = 0; it < 4; ++it) {
            const int j = jb + it * 32;
            const float4 pA = phiA[j];
            const float4 pB = phiB[j];
            short8 hv;
#pragma unroll
            for (int e = 0; e < 8; ++e) {
                float acc = b1r[e];
                acc = fmaf(pA.x, w1r[0][e], acc);
                acc = fmaf(pA.y, w1r[1][e], acc);
                acc = fmaf(pA.z, w1r[2][e], acc);
                acc = fmaf(pA.w, w1r[3][e], acc);
                acc = fmaf(pB.x, w1r[4][e], acc);
                acc = fmaf(pB.y, w1r[5][e], acc);
                acc = fmaf(pB.z, w1r[6][e], acc);
                acc = fmaf(pB.w, w1r[7][e], acc);
                const float ex = __expf(-acc);
                const float sv = acc * __builtin_amdgcn_rcpf(1.0f + ex);
                hv[e] = (short)f2bf_fast(sv);
            }
            if (j == i) hv = (short8){0, 0, 0, 0, 0, 0, 0, 0};
            const int byte = j * 128 + ((h0 * 2) ^ ((j & 7) << 4));
            *(short8*)((char*)hid_lds + byte) = hv;
        }
    }
    __syncthreads();

    // ---- fused phase B+C: per 16-row j-tile, MFMA then consume ----
    const int f    = w * 16 + (l & 15);
    const int jsub = (l >> 4) * 4;
    const float* sb = s_in + b * NN * FF;
    const float4* vb4 = (LAYER > 0) ? ((const float4*)v_in) + b * NN * FF : nullptr;

    float accs = 0.f, av0 = 0.f, av1 = 0.f, av2 = 0.f;

    // prefetch tile 0's s/v into registers
    float sP[4]; float4 vP[4];
#pragma unroll
    for (int reg = 0; reg < 4; ++reg) {
        const int j = jsub + reg;
        sP[reg] = sb[j * FF + f];
        if (LAYER > 0) vP[reg] = vb4[j * FF + f];
    }

#pragma unroll
    for (int mt = 0; mt < 8; ++mt) {
        // a-fragments for this 16-row tile (both K-slices)
        const int jA = mt * 16 + (l & 15);
        const int base = jA * 128;
        const int sw = (jA & 7) << 4;
        const short8 a0 = *(const short8*)((const char*)hid_lds + base + (((l >> 4) * 16 +  0) ^ sw));
        const short8 a1 = *(const short8*)((const char*)hid_lds + base + (((l >> 4) * 16 + 64) ^ sw));

        f32x4 c0 = (f32x4){0.f, 0.f, 0.f, 0.f};
        f32x4 c1 = (f32x4){0.f, 0.f, 0.f, 0.f};
        f32x4 c2 = (f32x4){0.f, 0.f, 0.f, 0.f};
        c0 = __builtin_amdgcn_mfma_f32_16x16x32_bf16(a0, bfrag[0][0], c0, 0, 0, 0);
        c0 = __builtin_amdgcn_mfma_f32_16x16x32_bf16(a1, bfrag[0][1], c0, 0, 0, 0);
        c1 = __builtin_amdgcn_mfma_f32_16x16x32_bf16(a0, bfrag[1][0], c1, 0, 0, 0);
        c1 = __builtin_amdgcn_mfma_f32_16x16x32_bf16(a1, bfrag[1][1], c1, 0, 0, 0);
        c2 = __builtin_amdgcn_mfma_f32_16x16x32_bf16(a0, bfrag[2][0], c2, 0, 0, 0);
        c2 = __builtin_amdgcn_mfma_f32_16x16x32_bf16(a1, bfrag[2][1], c2, 0, 0, 0);

        // prefetch next tile's s/v while MFMAs are in flight
        float sN[4]; float4 vN[4];
        if (mt < 7) {
#pragma unroll
            for (int reg = 0; reg < 4; ++reg) {
                const int j = (mt + 1) * 16 + jsub + reg;
                sN[reg] = sb[j * FF + f];
                if (LAYER > 0) vN[reg] = vb4[j * FF + f];
            }
        }

        // consume this tile's messages (lane covers 4 j rows)
#pragma unroll
        for (int reg = 0; reg < 4; ++reg) {
            const int j  = mt * 16 + jsub + reg;
            const float r1 = c0[reg];
            const float r2 = c1[reg];
            const float r3 = c2[reg];
            const float sj = sP[reg];
            const float r3s = r3 * sj;
            const float4 u = unit_lds[j];
            accs = fmaf(r1, sj, accs);
            av0 = fmaf(r3s, u.x, av0);
            av1 = fmaf(r3s, u.y, av1);
            av2 = fmaf(r3s, u.z, av2);
            if (LAYER > 0) {
                av0 = fmaf(r2, vP[reg].x, av0);
                av1 = fmaf(r2, vP[reg].y, av1);
                av2 = fmaf(r2, vP[reg].z, av2);
            }
        }
#pragma unroll
        for (int reg = 0; reg < 4; ++reg) {
            sP[reg] = sN[reg];
            if (LAYER > 0) vP[reg] = vN[reg];
        }
    }

    accs += __shfl_xor(accs, 16, 64); accs += __shfl_xor(accs, 32, 64);
    av0  += __shfl_xor(av0, 16, 64);  av0  += __shfl_xor(av0, 32, 64);
    av1  += __shfl_xor(av1, 16, 64);  av1  += __shfl_xor(av1, 32, 64);
    av2  += __shfl_xor(av2, 16, 64);  av2  += __shfl_xor(av2, 32, 64);
    if (l < 16) {
        // 1/127 already folded into W2 fragments
        ((float*)agg4)[0 * 64 + f] = accs;
        ((float*)agg4)[1 * 64 + f] = av0;
        ((float*)agg4)[2 * 64 + f] = av1;
        ((float*)agg4)[3 * 64 + f] = av2;
    }
    __syncthreads();

    // ---- tail: node update (+ readout for last layer), coalesced wT4 ------
    // wT4 layout: [m][ff4][g][4]; lane g loads float4 at (m*16+ff4)*64+g.
    const int g = l;
    const float4* wv4 = (const float4*)wT4;
    if (LAYER == 0) {
        const int m = (w == 0) ? 0 : 1;
        const int row = (w == 0) ? 0 : w;
        float a = (w == 0) ? s_in[node * FF + g] : 0.0f;
#pragma unroll
        for (int k = 0; k < 16; ++k) {
            const float4 w4 = wv4[(m * 16 + k) * 64 + g];
            const float4 a4 = agg4[row][k];
            a = fmaf(a4.x, w4.x, a); a = fmaf(a4.y, w4.y, a);
            a = fmaf(a4.z, w4.z, a); a = fmaf(a4.w, w4.w, a);
        }
        if (w == 0) s_out[node * FF + g] = a;
        else        v_out[(node * FF + g) * 4 + (w - 1)] = a;
    } else {
        if (w > 0) {
            const int d = w - 1;
            float a = v_in[(node * FF + g) * 4 + d];
#pragma unroll
            for (int k = 0; k < 16; ++k) {
                const float4 w4 = wv4[(16 + k) * 64 + g];
                const float4 a4 = agg4[w][k];
                a = fmaf(a4.x, w4.x, a); a = fmaf(a4.y, w4.y, a);
                a = fmaf(a4.z, w4.z, a); a = fmaf(a4.w, w4.w, a);
            }
            float p = a * wout[g];
#pragma unroll
            for (int off = 1; off < 64; off <<= 1)
                p += __shfl_xor(p, off, 64);
            if (l == 0)
                out[node * 3 + d] = (p - pos[node * 3 + d]) * scale[0];
        }
    }
}

extern "C" void kernel_launch(void* const* d_in, const int* in_sizes, int n_in,
                              void* d_out, int out_size, void* d_ws, size_t ws_size,
                              hipStream_t stream) {
    const float* pos     = (const float*)d_in[0];
    const int*   species = (const int*)  d_in[1];
    const float* glob    = (const float*)d_in[2];
    const float* embed   = (const float*)d_in[3];
    const float* glob_w  = (const float*)d_in[4];
    const float* rbf_w1  = (const float*)d_in[5];   // [2][8][64]
    const float* rbf_b1  = (const float*)d_in[6];   // [2][64]
    const float* rbf_w2  = (const float*)d_in[7];   // [2][64][192]
    const float* ws      = (const float*)d_in[8];   // [2][64][64]
    const float* wv      = (const float*)d_in[9];   // [2][64][64]
    const float* wout    = (const float*)d_in[10];  // [64]
    const float* scale   = (const float*)d_in[11];  // [1]

    float* wsf = (float*)d_ws;
    float* s0     = wsf;                   // 262144 floats
    float* s1     = wsf + 262144;          // 262144
    float* v1     = wsf + 524288;          // 1048576
    short* w2frag = (short*)(wsf + 1572864);   // 24576 shorts (12288 floats)
    float* wT4    = wsf + 1572864 + 12288;     // 16384 floats
    float* outp = (float*)d_out;

    prep_kernel<<<dim3(160), 256, 0, stream>>>(rbf_w2, ws, wv, w2frag, wT4);
    init_kernel<<<dim3(BB * NN / 4), 256, 0, stream>>>(species, glob, embed, glob_w, s0);

    msg_kernel<0><<<dim3(NN, BB), 256, 0, stream>>>(
        pos, s0, nullptr,
        rbf_w1, rbf_b1, w2frag, wT4, wout, scale,
        s1, v1, nullptr);

    msg_kernel<1><<<dim3(NN, BB), 256, 0, stream>>>(
        pos, s1, v1,
        rbf_w1 + 8 * 64, rbf_b1 + 64, w2frag + 12288, wT4 + 8192, wout, scale,
        nullptr, nullptr, outp);
}

// Round 7
// 99.056 us; speedup vs baseline: 3.1946x; 3.1946x over previous
//
#include <hip/hip_runtime.h>
#include <hip/hip_bf16.h>

// MACE-like GNN on MI355X — MFMA + prep-baked weights.
// B=32, N=128, F=64, N_RBF=8, H_R=64, L=2.
// Round 7: round 6's coalesced wT4 tail, launch_bounds reverted to (256,4)
// (the ",6" forced VGPR<=40 -> 1GB spill traffic; see round-6 post-mortem).

#define NN 128
#define BB 32
#define FF 64

using f32x4  = __attribute__((ext_vector_type(4))) float;
using short8 = __attribute__((ext_vector_type(8))) short;

__device__ __forceinline__ unsigned short f2bf(float x) {
    unsigned int u = __float_as_uint(x);
    u += 0x7fff + ((u >> 16) & 1);          // RNE
    return (unsigned short)(u >> 16);
}
__device__ __forceinline__ unsigned short f2bf_fast(float x) {
    return (unsigned short)((__float_as_uint(x) + 0x8000u) >> 16);
}

// -------------------- prep: bake weights into fast layouts -----------------
// w2frag: [layer][wave][nt][ks][lane][e]  bf16, scaled by 1/127
// wT4:    [layer][m(0=ws,1=wv)][ff4][g][4]  f32; element (.,c) = w[(ff4*4+c)*64+g]
__global__ __launch_bounds__(256) void prep_kernel(
    const float* __restrict__ w2,    // [2][64][192]
    const float* __restrict__ ws,    // [2][64][64]
    const float* __restrict__ wv,    // [2][64][64]
    short* __restrict__ w2frag,      // [2][4][3][2][64][8] = 24576 shorts
    float* __restrict__ wT4)         // [2][2][16][64][4]   = 16384 floats
{
    const int tid = blockIdx.x * 256 + threadIdx.x;
    const int NFRAG = 24576;
    if (tid < NFRAG) {
        const int e  = tid & 7;
        const int l  = (tid >> 3) & 63;
        const int ks = (tid >> 9) & 1;
        const int q  = tid >> 10;          // layer*12 + wave*3 + nt
        const int nt = q % 3;
        const int wv_ = (q / 3) & 3;
        const int layer = q / 12;
        const int col = nt * 64 + wv_ * 16 + (l & 15);
        const int hb  = ks * 32 + (l >> 4) * 8 + e;
        const float val = w2[layer * 64 * 192 + hb * 192 + col] * (1.0f / 127.0f);
        w2frag[tid] = (short)f2bf(val);
    }
    const int tid2 = tid - NFRAG;
    if (tid2 >= 0 && tid2 < 16384) {
        const int c   = tid2 & 3;
        const int g   = (tid2 >> 2) & 63;
        const int ff4 = (tid2 >> 8) & 15;
        const int m   = (tid2 >> 12) & 1;
        const int layer = tid2 >> 13;
        const float* src = (m == 0 ? ws : wv) + layer * 4096;
        wT4[tid2] = src[(ff4 * 4 + c) * 64 + g];
    }
}

// -------------------- init: s = embed[species] + glob @ glob_w -------------
__global__ __launch_bounds__(256) void init_kernel(
    const int* __restrict__ species, const float* __restrict__ glob,
    const float* __restrict__ embed, const float* __restrict__ glob_w,
    float* __restrict__ s)
{
    const int node = blockIdx.x * 4 + (threadIdx.x >> 6);   // b*128 + n
    const int b = node >> 7;
    const int f = threadIdx.x & 63;
    const int sp = species[node];
    float acc = embed[sp * FF + f];
#pragma unroll
    for (int k = 0; k < 16; ++k)
        acc = fmaf(glob[b * 16 + k], glob_w[k * FF + f], acc);
    s[node * FF + f] = acc;
}

// -------------------- fused message+agg+update (+readout for LAYER==1) ----
// grid (128 receivers, 32 batch), block 256 = 4 waves.
// wave w owns channels f in [16w, 16w+16).
template<int LAYER>
__global__ __launch_bounds__(256, 4) void msg_kernel(
    const float* __restrict__ pos,     // [B][N][3]
    const float* __restrict__ s_in,    // [B][N][F]
    const float* __restrict__ v_in,    // [B][N][F][4]  (unused when LAYER==0)
    const float* __restrict__ w1,      // [8][64]
    const float* __restrict__ b1,      // [64]
    const short* __restrict__ w2frag,  // [4][3][2][64][8] bf16 (layer slice)
    const float* __restrict__ wT4,     // [2][16][64][4] (ws,wv; layer slice)
    const float* __restrict__ wout,    // [64]
    const float* __restrict__ scale,   // [1]
    float* __restrict__ s_out,         // LAYER==0 only
    float* __restrict__ v_out,         // LAYER==0 only, [B][N][F][4]
    float* __restrict__ out)           // LAYER==1 only
{
    __shared__ unsigned short hid_lds[NN * 64];   // 16 KB, XOR-swizzled rows
    __shared__ float4 unit_lds[NN];
    __shared__ float4 phiA[NN], phiB[NN];
    __shared__ float4 agg4[4][16];

    const int i = blockIdx.x;
    const int b = blockIdx.y;
    const int t = threadIdx.x;
    const int w = t >> 6;          // wave
    const int l = t & 63;          // lane
    const int node = b * NN + i;
    const float* pb = pos + b * NN * 3;

    // ---- B fragments: pre-baked, 6 coalesced 16B loads (hide under A1/A2) --
    short8 bfrag[3][2];
    {
        const short8* wf = (const short8*)w2frag;
#pragma unroll
        for (int nt = 0; nt < 3; ++nt)
#pragma unroll
            for (int ks = 0; ks < 2; ++ks)
                bfrag[nt][ks] = wf[((w * 3 + nt) * 2 + ks) * 64 + l];
    }

    // ---- phase A1: per-edge distance, unit vector, and RBF (once per j) ---
    if (t < NN) {
        const int j = t;
        const float dx = pb[i * 3 + 0] - pb[j * 3 + 0];
        const float dy = pb[i * 3 + 1] - pb[j * 3 + 1];
        const float dz = pb[i * 3 + 2] - pb[j * 3 + 2];
        const float d2 = fmaf(dx, dx, fmaf(dy, dy, fmaf(dz, dz, 1e-12f)));
        const float inv = __builtin_amdgcn_rsqf(d2);
        const float dd = d2 * inv;
        unit_lds[j] = make_float4(dx * inv, dy * inv, dz * inv, 0.0f);
        float ph[8];
#pragma unroll
        for (int r = 0; r < 8; ++r) {
            const float td = dd - (float)r * (5.0f / 7.0f);
            ph[r] = __expf(td * td * -1.28f);   // 1/(2*0.625^2) = 1.28
        }
        phiA[j] = make_float4(ph[0], ph[1], ph[2], ph[3]);
        phiB[j] = make_float4(ph[4], ph[5], ph[6], ph[7]);
    }
    __syncthreads();

    // ---- phase A2: hid[j][h] = silu(phi(d_j) @ W1 + b1), bf16 -> LDS ----
    {
        const int h0 = (t & 7) * 8;    // h-chunk (8 units)
        const int jb = t >> 3;         // 0..31
        float w1r[8][8];
#pragma unroll
        for (int r = 0; r < 8; ++r) {
            const float4 a0 = *(const float4*)(w1 + r * 64 + h0);
            const float4 a1 = *(const float4*)(w1 + r * 64 + h0 + 4);
            w1r[r][0] = a0.x; w1r[r][1] = a0.y; w1r[r][2] = a0.z; w1r[r][3] = a0.w;
            w1r[r][4] = a1.x; w1r[r][5] = a1.y; w1r[r][6] = a1.z; w1r[r][7] = a1.w;
        }
        float b1r[8];
        {
            const float4 c0 = *(const float4*)(b1 + h0);
            const float4 c1 = *(const float4*)(b1 + h0 + 4);
            b1r[0] = c0.x; b1r[1] = c0.y; b1r[2] = c0.z; b1r[3] = c0.w;
            b1r[4] = c1.x; b1r[5] = c1.y; b1r[6] = c1.z; b1r[7] = c1.w;
        }
#pragma unroll
        for (int it = 0; it < 4; ++it) {
            const int j = jb + it * 32;
            const float4 pA = phiA[j];
            const float4 pB = phiB[j];
            short8 hv;
#pragma unroll
            for (int e = 0; e < 8; ++e) {
                float acc = b1r[e];
                acc = fmaf(pA.x, w1r[0][e], acc);
                acc = fmaf(pA.y, w1r[1][e], acc);
                acc = fmaf(pA.z, w1r[2][e], acc);
                acc = fmaf(pA.w, w1r[3][e], acc);
                acc = fmaf(pB.x, w1r[4][e], acc);
                acc = fmaf(pB.y, w1r[5][e], acc);
                acc = fmaf(pB.z, w1r[6][e], acc);
                acc = fmaf(pB.w, w1r[7][e], acc);
                const float ex = __expf(-acc);
                const float sv = acc * __builtin_amdgcn_rcpf(1.0f + ex);
                hv[e] = (short)f2bf_fast(sv);
            }
            if (j == i) hv = (short8){0, 0, 0, 0, 0, 0, 0, 0};
            const int byte = j * 128 + ((h0 * 2) ^ ((j & 7) << 4));
            *(short8*)((char*)hid_lds + byte) = hv;
        }
    }
    __syncthreads();

    // ---- fused phase B+C: per 16-row j-tile, MFMA then consume ----
    const int f    = w * 16 + (l & 15);
    const int jsub = (l >> 4) * 4;
    const float* sb = s_in + b * NN * FF;
    const float4* vb4 = (LAYER > 0) ? ((const float4*)v_in) + b * NN * FF : nullptr;

    float accs = 0.f, av0 = 0.f, av1 = 0.f, av2 = 0.f;

    // prefetch tile 0's s/v into registers
    float sP[4]; float4 vP[4];
#pragma unroll
    for (int reg = 0; reg < 4; ++reg) {
        const int j = jsub + reg;
        sP[reg] = sb[j * FF + f];
        if (LAYER > 0) vP[reg] = vb4[j * FF + f];
    }

#pragma unroll
    for (int mt = 0; mt < 8; ++mt) {
        // a-fragments for this 16-row tile (both K-slices)
        const int jA = mt * 16 + (l & 15);
        const int base = jA * 128;
        const int sw = (jA & 7) << 4;
        const short8 a0 = *(const short8*)((const char*)hid_lds + base + (((l >> 4) * 16 +  0) ^ sw));
        const short8 a1 = *(const short8*)((const char*)hid_lds + base + (((l >> 4) * 16 + 64) ^ sw));

        f32x4 c0 = (f32x4){0.f, 0.f, 0.f, 0.f};
        f32x4 c1 = (f32x4){0.f, 0.f, 0.f, 0.f};
        f32x4 c2 = (f32x4){0.f, 0.f, 0.f, 0.f};
        c0 = __builtin_amdgcn_mfma_f32_16x16x32_bf16(a0, bfrag[0][0], c0, 0, 0, 0);
        c0 = __builtin_amdgcn_mfma_f32_16x16x32_bf16(a1, bfrag[0][1], c0, 0, 0, 0);
        c1 = __builtin_amdgcn_mfma_f32_16x16x32_bf16(a0, bfrag[1][0], c1, 0, 0, 0);
        c1 = __builtin_amdgcn_mfma_f32_16x16x32_bf16(a1, bfrag[1][1], c1, 0, 0, 0);
        c2 = __builtin_amdgcn_mfma_f32_16x16x32_bf16(a0, bfrag[2][0], c2, 0, 0, 0);
        c2 = __builtin_amdgcn_mfma_f32_16x16x32_bf16(a1, bfrag[2][1], c2, 0, 0, 0);

        // prefetch next tile's s/v while MFMAs are in flight
        float sN[4]; float4 vN[4];
        if (mt < 7) {
#pragma unroll
            for (int reg = 0; reg < 4; ++reg) {
                const int j = (mt + 1) * 16 + jsub + reg;
                sN[reg] = sb[j * FF + f];
                if (LAYER > 0) vN[reg] = vb4[j * FF + f];
            }
        }

        // consume this tile's messages (lane covers 4 j rows)
#pragma unroll
        for (int reg = 0; reg < 4; ++reg) {
            const int j  = mt * 16 + jsub + reg;
            const float r1 = c0[reg];
            const float r2 = c1[reg];
            const float r3 = c2[reg];
            const float sj = sP[reg];
            const float r3s = r3 * sj;
            const float4 u = unit_lds[j];
            accs = fmaf(r1, sj, accs);
            av0 = fmaf(r3s, u.x, av0);
            av1 = fmaf(r3s, u.y, av1);
            av2 = fmaf(r3s, u.z, av2);
            if (LAYER > 0) {
                av0 = fmaf(r2, vP[reg].x, av0);
                av1 = fmaf(r2, vP[reg].y, av1);
                av2 = fmaf(r2, vP[reg].z, av2);
            }
        }
#pragma unroll
        for (int reg = 0; reg < 4; ++reg) {
            sP[reg] = sN[reg];
            if (LAYER > 0) vP[reg] = vN[reg];
        }
    }

    accs += __shfl_xor(accs, 16, 64); accs += __shfl_xor(accs, 32, 64);
    av0  += __shfl_xor(av0, 16, 64);  av0  += __shfl_xor(av0, 32, 64);
    av1  += __shfl_xor(av1, 16, 64);  av1  += __shfl_xor(av1, 32, 64);
    av2  += __shfl_xor(av2, 16, 64);  av2  += __shfl_xor(av2, 32, 64);
    if (l < 16) {
        // 1/127 already folded into W2 fragments
        ((float*)agg4)[0 * 64 + f] = accs;
        ((float*)agg4)[1 * 64 + f] = av0;
        ((float*)agg4)[2 * 64 + f] = av1;
        ((float*)agg4)[3 * 64 + f] = av2;
    }
    __syncthreads();

    // ---- tail: node update (+ readout for last layer), coalesced wT4 ------
    // wT4 layout: [m][ff4][g][4]; lane g loads float4 at (m*16+ff4)*64+g.
    const int g = l;
    const float4* wv4 = (const float4*)wT4;
    if (LAYER == 0) {
        const int m = (w == 0) ? 0 : 1;
        const int row = (w == 0) ? 0 : w;
        float a = (w == 0) ? s_in[node * FF + g] : 0.0f;
#pragma unroll
        for (int k = 0; k < 16; ++k) {
            const float4 w4 = wv4[(m * 16 + k) * 64 + g];
            const float4 a4 = agg4[row][k];
            a = fmaf(a4.x, w4.x, a); a = fmaf(a4.y, w4.y, a);
            a = fmaf(a4.z, w4.z, a); a = fmaf(a4.w, w4.w, a);
        }
        if (w == 0) s_out[node * FF + g] = a;
        else        v_out[(node * FF + g) * 4 + (w - 1)] = a;
    } else {
        if (w > 0) {
            const int d = w - 1;
            float a = v_in[(node * FF + g) * 4 + d];
#pragma unroll
            for (int k = 0; k < 16; ++k) {
                const float4 w4 = wv4[(16 + k) * 64 + g];
                const float4 a4 = agg4[w][k];
                a = fmaf(a4.x, w4.x, a); a = fmaf(a4.y, w4.y, a);
                a = fmaf(a4.z, w4.z, a); a = fmaf(a4.w, w4.w, a);
            }
            float p = a * wout[g];
#pragma unroll
            for (int off = 1; off < 64; off <<= 1)
                p += __shfl_xor(p, off, 64);
            if (l == 0)
                out[node * 3 + d] = (p - pos[node * 3 + d]) * scale[0];
        }
    }
}

extern "C" void kernel_launch(void* const* d_in, const int* in_sizes, int n_in,
                              void* d_out, int out_size, void* d_ws, size_t ws_size,
                              hipStream_t stream) {
    const float* pos     = (const float*)d_in[0];
    const int*   species = (const int*)  d_in[1];
    const float* glob    = (const float*)d_in[2];
    const float* embed   = (const float*)d_in[3];
    const float* glob_w  = (const float*)d_in[4];
    const float* rbf_w1  = (const float*)d_in[5];   // [2][8][64]
    const float* rbf_b1  = (const float*)d_in[6];   // [2][64]
    const float* rbf_w2  = (const float*)d_in[7];   // [2][64][192]
    const float* ws      = (const float*)d_in[8];   // [2][64][64]
    const float* wv      = (const float*)d_in[9];   // [2][64][64]
    const float* wout    = (const float*)d_in[10];  // [64]
    const float* scale   = (const float*)d_in[11];  // [1]

    float* wsf = (float*)d_ws;
    float* s0     = wsf;                   // 262144 floats
    float* s1     = wsf + 262144;          // 262144
    float* v1     = wsf + 524288;          // 1048576
    short* w2frag = (short*)(wsf + 1572864);   // 24576 shorts (12288 floats)
    float* wT4    = wsf + 1572864 + 12288;     // 16384 floats
    float* outp = (float*)d_out;

    prep_kernel<<<dim3(160), 256, 0, stream>>>(rbf_w2, ws, wv, w2frag, wT4);
    init_kernel<<<dim3(BB * NN / 4), 256, 0, stream>>>(species, glob, embed, glob_w, s0);

    msg_kernel<0><<<dim3(NN, BB), 256, 0, stream>>>(
        pos, s0, nullptr,
        rbf_w1, rbf_b1, w2frag, wT4, wout, scale,
        s1, v1, nullptr);

    msg_kernel<1><<<dim3(NN, BB), 256, 0, stream>>>(
        pos, s1, v1,
        rbf_w1 + 8 * 64, rbf_b1 + 64, w2frag + 12288, wT4 + 8192, wout, scale,
        nullptr, nullptr, outp);
}

// Round 8
// 93.748 us; speedup vs baseline: 3.3754x; 1.0566x over previous
//
#include <hip/hip_runtime.h>
#include <hip/hip_bf16.h>

// MACE-like GNN on MI355X — MFMA + prep-baked weights.
// B=32, N=128, F=64, N_RBF=8, H_R=64, L=2.
// Round 8: setup-kernel merge (prep+init), XCD-aware block swizzle
// (4 batches per XCD -> per-XCD L2 working set 640KB), A1 on all 256 threads.

#define NN 128
#define BB 32
#define FF 64

using f32x4  = __attribute__((ext_vector_type(4))) float;
using short8 = __attribute__((ext_vector_type(8))) short;

__device__ __forceinline__ unsigned short f2bf(float x) {
    unsigned int u = __float_as_uint(x);
    u += 0x7fff + ((u >> 16) & 1);          // RNE
    return (unsigned short)(u >> 16);
}
__device__ __forceinline__ unsigned short f2bf_fast(float x) {
    return (unsigned short)((__float_as_uint(x) + 0x8000u) >> 16);
}

// -------------------- setup: prep weights + init node scalars --------------
// blocks [0,160):   w2frag/wT4 bake
// blocks [160,1184): s0 = embed[species] + glob @ glob_w
__global__ __launch_bounds__(256) void setup_kernel(
    const float* __restrict__ w2,    // [2][64][192]
    const float* __restrict__ ws,    // [2][64][64]
    const float* __restrict__ wv,    // [2][64][64]
    const int* __restrict__ species, const float* __restrict__ glob,
    const float* __restrict__ embed, const float* __restrict__ glob_w,
    short* __restrict__ w2frag,      // [2][4][3][2][64][8] = 24576 shorts
    float* __restrict__ wT4,         // [2][2][16][64][4]   = 16384 floats
    float* __restrict__ s)           // [B*N][64]
{
    const int blk = blockIdx.x;
    if (blk < 160) {
        const int tid = blk * 256 + threadIdx.x;
        const int NFRAG = 24576;
        if (tid < NFRAG) {
            const int e  = tid & 7;
            const int l  = (tid >> 3) & 63;
            const int ks = (tid >> 9) & 1;
            const int q  = tid >> 10;          // layer*12 + wave*3 + nt
            const int nt = q % 3;
            const int wv_ = (q / 3) & 3;
            const int layer = q / 12;
            const int col = nt * 64 + wv_ * 16 + (l & 15);
            const int hb  = ks * 32 + (l >> 4) * 8 + e;
            const float val = w2[layer * 64 * 192 + hb * 192 + col] * (1.0f / 127.0f);
            w2frag[tid] = (short)f2bf(val);
        }
        const int tid2 = tid - NFRAG;
        if (tid2 >= 0 && tid2 < 16384) {
            const int c   = tid2 & 3;
            const int g   = (tid2 >> 2) & 63;
            const int ff4 = (tid2 >> 8) & 15;
            const int m   = (tid2 >> 12) & 1;
            const int layer = tid2 >> 13;
            const float* src = (m == 0 ? ws : wv) + layer * 4096;
            wT4[tid2] = src[(ff4 * 4 + c) * 64 + g];
        }
    } else {
        const int node = (blk - 160) * 4 + (threadIdx.x >> 6);   // b*128 + n
        const int b = node >> 7;
        const int f = threadIdx.x & 63;
        const int sp = species[node];
        float acc = embed[sp * FF + f];
#pragma unroll
        for (int k = 0; k < 16; ++k)
            acc = fmaf(glob[b * 16 + k], glob_w[k * FF + f], acc);
        s[node * FF + f] = acc;
    }
}

// -------------------- fused message+agg+update (+readout for LAYER==1) ----
// grid 4096 (XCD-swizzled), block 256 = 4 waves.
// wave w owns channels f in [16w, 16w+16).
template<int LAYER>
__global__ __launch_bounds__(256, 4) void msg_kernel(
    const float* __restrict__ pos,     // [B][N][3]
    const float* __restrict__ s_in,    // [B][N][F]
    const float* __restrict__ v_in,    // [B][N][F][4]  (unused when LAYER==0)
    const float* __restrict__ w1,      // [8][64]
    const float* __restrict__ b1,      // [64]
    const short* __restrict__ w2frag,  // [4][3][2][64][8] bf16 (layer slice)
    const float* __restrict__ wT4,     // [2][16][64][4] (ws,wv; layer slice)
    const float* __restrict__ wout,    // [64]
    const float* __restrict__ scale,   // [1]
    float* __restrict__ s_out,         // LAYER==0 only
    float* __restrict__ v_out,         // LAYER==0 only, [B][N][F][4]
    float* __restrict__ out)           // LAYER==1 only
{
    __shared__ unsigned short hid_lds[NN * 64];   // 16 KB, XOR-swizzled rows
    __shared__ float4 unit_lds[NN];
    __shared__ float4 phiA[NN], phiB[NN];
    __shared__ float4 agg4[4][16];

    // XCD-aware swizzle: xcd = blk&7 (empirical dispatch round-robin);
    // each XCD owns 4 consecutive batches -> L2 working set ~640KB.
    const int blk = blockIdx.x;
    const int xcd = blk & 7;
    const int idx = blk >> 3;            // 0..511
    const int b = xcd * 4 + (idx >> 7);
    const int i = idx & 127;

    const int t = threadIdx.x;
    const int w = t >> 6;          // wave
    const int l = t & 63;          // lane
    const int node = b * NN + i;
    const float* pb = pos + b * NN * 3;

    // ---- B fragments: pre-baked, 6 coalesced 16B loads (hide under A1/A2) --
    short8 bfrag[3][2];
    {
        const short8* wf = (const short8*)w2frag;
#pragma unroll
        for (int nt = 0; nt < 3; ++nt)
#pragma unroll
            for (int ks = 0; ks < 2; ++ks)
                bfrag[nt][ks] = wf[((w * 3 + nt) * 2 + ks) * 64 + l];
    }

    // ---- phase A1: distance/unit/RBF; thread pairs (t, t+128) split r 4/4 --
    {
        const int j = t & 127;
        const int half = t >> 7;
        const float dx = pb[i * 3 + 0] - pb[j * 3 + 0];
        const float dy = pb[i * 3 + 1] - pb[j * 3 + 1];
        const float dz = pb[i * 3 + 2] - pb[j * 3 + 2];
        const float d2 = fmaf(dx, dx, fmaf(dy, dy, fmaf(dz, dz, 1e-12f)));
        const float inv = __builtin_amdgcn_rsqf(d2);
        const float dd = d2 * inv;
        float ph[4];
#pragma unroll
        for (int r = 0; r < 4; ++r) {
            const float td = dd - (float)(half * 4 + r) * (5.0f / 7.0f);
            ph[r] = __expf(td * td * -1.28f);   // 1/(2*0.625^2) = 1.28
        }
        if (half == 0) {
            unit_lds[j] = make_float4(dx * inv, dy * inv, dz * inv, 0.0f);
            phiA[j] = make_float4(ph[0], ph[1], ph[2], ph[3]);
        } else {
            phiB[j] = make_float4(ph[0], ph[1], ph[2], ph[3]);
        }
    }
    __syncthreads();

    // ---- phase A2: hid[j][h] = silu(phi(d_j) @ W1 + b1), bf16 -> LDS ----
    {
        const int h0 = (t & 7) * 8;    // h-chunk (8 units)
        const int jb = t >> 3;         // 0..31
        float w1r[8][8];
#pragma unroll
        for (int r = 0; r < 8; ++r) {
            const float4 a0 = *(const float4*)(w1 + r * 64 + h0);
            const float4 a1 = *(const float4*)(w1 + r * 64 + h0 + 4);
            w1r[r][0] = a0.x; w1r[r][1] = a0.y; w1r[r][2] = a0.z; w1r[r][3] = a0.w;
            w1r[r][4] = a1.x; w1r[r][5] = a1.y; w1r[r][6] = a1.z; w1r[r][7] = a1.w;
        }
        float b1r[8];
        {
            const float4 c0 = *(const float4*)(b1 + h0);
            const float4 c1 = *(const float4*)(b1 + h0 + 4);
            b1r[0] = c0.x; b1r[1] = c0.y; b1r[2] = c0.z; b1r[3] = c0.w;
            b1r[4] = c1.x; b1r[5] = c1.y; b1r[6] = c1.z; b1r[7] = c1.w;
        }
#pragma unroll
        for (int it = 0; it < 4; ++it) {
            const int j = jb + it * 32;
            const float4 pA = phiA[j];
            const float4 pB = phiB[j];
            short8 hv;
#pragma unroll
            for (int e = 0; e < 8; ++e) {
                float acc = b1r[e];
                acc = fmaf(pA.x, w1r[0][e], acc);
                acc = fmaf(pA.y, w1r[1][e], acc);
                acc = fmaf(pA.z, w1r[2][e], acc);
                acc = fmaf(pA.w, w1r[3][e], acc);
                acc = fmaf(pB.x, w1r[4][e], acc);
                acc = fmaf(pB.y, w1r[5][e], acc);
                acc = fmaf(pB.z, w1r[6][e], acc);
                acc = fmaf(pB.w, w1r[7][e], acc);
                const float ex = __expf(-acc);
                const float sv = acc * __builtin_amdgcn_rcpf(1.0f + ex);
                hv[e] = (short)f2bf_fast(sv);
            }
            if (j == i) hv = (short8){0, 0, 0, 0, 0, 0, 0, 0};
            const int byte = j * 128 + ((h0 * 2) ^ ((j & 7) << 4));
            *(short8*)((char*)hid_lds + byte) = hv;
        }
    }
    __syncthreads();

    // ---- fused phase B+C: per 16-row j-tile, MFMA then consume ----
    const int f    = w * 16 + (l & 15);
    const int jsub = (l >> 4) * 4;
    const float* sb = s_in + b * NN * FF;
    const float4* vb4 = (LAYER > 0) ? ((const float4*)v_in) + b * NN * FF : nullptr;

    float accs = 0.f, av0 = 0.f, av1 = 0.f, av2 = 0.f;

    // prefetch tile 0's s/v into registers
    float sP[4]; float4 vP[4];
#pragma unroll
    for (int reg = 0; reg < 4; ++reg) {
        const int j = jsub + reg;
        sP[reg] = sb[j * FF + f];
        if (LAYER > 0) vP[reg] = vb4[j * FF + f];
    }

#pragma unroll
    for (int mt = 0; mt < 8; ++mt) {
        // a-fragments for this 16-row tile (both K-slices)
        const int jA = mt * 16 + (l & 15);
        const int base = jA * 128;
        const int sw = (jA & 7) << 4;
        const short8 a0 = *(const short8*)((const char*)hid_lds + base + (((l >> 4) * 16 +  0) ^ sw));
        const short8 a1 = *(const short8*)((const char*)hid_lds + base + (((l >> 4) * 16 + 64) ^ sw));

        f32x4 c0 = (f32x4){0.f, 0.f, 0.f, 0.f};
        f32x4 c1 = (f32x4){0.f, 0.f, 0.f, 0.f};
        f32x4 c2 = (f32x4){0.f, 0.f, 0.f, 0.f};
        c0 = __builtin_amdgcn_mfma_f32_16x16x32_bf16(a0, bfrag[0][0], c0, 0, 0, 0);
        c0 = __builtin_amdgcn_mfma_f32_16x16x32_bf16(a1, bfrag[0][1], c0, 0, 0, 0);
        c1 = __builtin_amdgcn_mfma_f32_16x16x32_bf16(a0, bfrag[1][0], c1, 0, 0, 0);
        c1 = __builtin_amdgcn_mfma_f32_16x16x32_bf16(a1, bfrag[1][1], c1, 0, 0, 0);
        c2 = __builtin_amdgcn_mfma_f32_16x16x32_bf16(a0, bfrag[2][0], c2, 0, 0, 0);
        c2 = __builtin_amdgcn_mfma_f32_16x16x32_bf16(a1, bfrag[2][1], c2, 0, 0, 0);

        // prefetch next tile's s/v while MFMAs are in flight
        float sN[4]; float4 vN[4];
        if (mt < 7) {
#pragma unroll
            for (int reg = 0; reg < 4; ++reg) {
                const int j = (mt + 1) * 16 + jsub + reg;
                sN[reg] = sb[j * FF + f];
                if (LAYER > 0) vN[reg] = vb4[j * FF + f];
            }
        }

        // consume this tile's messages (lane covers 4 j rows)
#pragma unroll
        for (int reg = 0; reg < 4; ++reg) {
            const int j  = mt * 16 + jsub + reg;
            const float r1 = c0[reg];
            const float r2 = c1[reg];
            const float r3 = c2[reg];
            const float sj = sP[reg];
            const float r3s = r3 * sj;
            const float4 u = unit_lds[j];
            accs = fmaf(r1, sj, accs);
            av0 = fmaf(r3s, u.x, av0);
            av1 = fmaf(r3s, u.y, av1);
            av2 = fmaf(r3s, u.z, av2);
            if (LAYER > 0) {
                av0 = fmaf(r2, vP[reg].x, av0);
                av1 = fmaf(r2, vP[reg].y, av1);
                av2 = fmaf(r2, vP[reg].z, av2);
            }
        }
#pragma unroll
        for (int reg = 0; reg < 4; ++reg) {
            sP[reg] = sN[reg];
            if (LAYER > 0) vP[reg] = vN[reg];
        }
    }

    accs += __shfl_xor(accs, 16, 64); accs += __shfl_xor(accs, 32, 64);
    av0  += __shfl_xor(av0, 16, 64);  av0  += __shfl_xor(av0, 32, 64);
    av1  += __shfl_xor(av1, 16, 64);  av1  += __shfl_xor(av1, 32, 64);
    av2  += __shfl_xor(av2, 16, 64);  av2  += __shfl_xor(av2, 32, 64);
    if (l < 16) {
        // 1/127 already folded into W2 fragments
        ((float*)agg4)[0 * 64 + f] = accs;
        ((float*)agg4)[1 * 64 + f] = av0;
        ((float*)agg4)[2 * 64 + f] = av1;
        ((float*)agg4)[3 * 64 + f] = av2;
    }
    __syncthreads();

    // ---- tail: node update (+ readout for last layer), coalesced wT4 ------
    // wT4 layout: [m][ff4][g][4]; lane g loads float4 at (m*16+ff4)*64+g.
    const int g = l;
    const float4* wv4 = (const float4*)wT4;
    if (LAYER == 0) {
        const int m = (w == 0) ? 0 : 1;
        const int row = (w == 0) ? 0 : w;
        float a = (w == 0) ? s_in[node * FF + g] : 0.0f;
#pragma unroll
        for (int k = 0; k < 16; ++k) {
            const float4 w4 = wv4[(m * 16 + k) * 64 + g];
            const float4 a4 = agg4[row][k];
            a = fmaf(a4.x, w4.x, a); a = fmaf(a4.y, w4.y, a);
            a = fmaf(a4.z, w4.z, a); a = fmaf(a4.w, w4.w, a);
        }
        if (w == 0) s_out[node * FF + g] = a;
        else        v_out[(node * FF + g) * 4 + (w - 1)] = a;
    } else {
        if (w > 0) {
            const int d = w - 1;
            float a = v_in[(node * FF + g) * 4 + d];
#pragma unroll
            for (int k = 0; k < 16; ++k) {
                const float4 w4 = wv4[(16 + k) * 64 + g];
                const float4 a4 = agg4[w][k];
                a = fmaf(a4.x, w4.x, a); a = fmaf(a4.y, w4.y, a);
                a = fmaf(a4.z, w4.z, a); a = fmaf(a4.w, w4.w, a);
            }
            float p = a * wout[g];
#pragma unroll
            for (int off = 1; off < 64; off <<= 1)
                p += __shfl_xor(p, off, 64);
            if (l == 0)
                out[node * 3 + d] = (p - pos[node * 3 + d]) * scale[0];
        }
    }
}

extern "C" void kernel_launch(void* const* d_in, const int* in_sizes, int n_in,
                              void* d_out, int out_size, void* d_ws, size_t ws_size,
                              hipStream_t stream) {
    const float* pos     = (const float*)d_in[0];
    const int*   species = (const int*)  d_in[1];
    const float* glob    = (const float*)d_in[2];
    const float* embed   = (const float*)d_in[3];
    const float* glob_w  = (const float*)d_in[4];
    const float* rbf_w1  = (const float*)d_in[5];   // [2][8][64]
    const float* rbf_b1  = (const float*)d_in[6];   // [2][64]
    const float* rbf_w2  = (const float*)d_in[7];   // [2][64][192]
    const float* ws      = (const float*)d_in[8];   // [2][64][64]
    const float* wv      = (const float*)d_in[9];   // [2][64][64]
    const float* wout    = (const float*)d_in[10];  // [64]
    const float* scale   = (const float*)d_in[11];  // [1]

    float* wsf = (float*)d_ws;
    float* s0     = wsf;                   // 262144 floats
    float* s1     = wsf + 262144;          // 262144
    float* v1     = wsf + 524288;          // 1048576
    short* w2frag = (short*)(wsf + 1572864);   // 24576 shorts (12288 floats)
    float* wT4    = wsf + 1572864 + 12288;     // 16384 floats
    float* outp = (float*)d_out;

    setup_kernel<<<dim3(160 + BB * NN / 4), 256, 0, stream>>>(
        rbf_w2, ws, wv, species, glob, embed, glob_w, w2frag, wT4, s0);

    msg_kernel<0><<<dim3(NN * BB), 256, 0, stream>>>(
        pos, s0, nullptr,
        rbf_w1, rbf_b1, w2frag, wT4, wout, scale,
        s1, v1, nullptr);

    msg_kernel<1><<<dim3(NN * BB), 256, 0, stream>>>(
        pos, s1, v1,
        rbf_w1 + 8 * 64, rbf_b1 + 64, w2frag + 12288, wT4 + 8192, wout, scale,
        nullptr, nullptr, outp);
}

// Round 9
// 82.909 us; speedup vs baseline: 3.8167x; 1.1307x over previous
//
#include <hip/hip_runtime.h>
#include <hip/hip_bf16.h>

// MACE-like GNN on MI355X — MFMA for BOTH GEMMs (phi@W1 and hid@W2).
// B=32, N=128, F=64, N_RBF=8, H_R=64, L=2.
// Round 9: phase A2 (radial-MLP layer 1) moved to matrix cores:
//   preact = [phi | 1] @ [W1 ; b1]  via mfma_f32_16x16x32_f16 (K padded to 32),
//   bias as W1-row 8 so zeroing phi row i zeroes hid[i] for free.

#define NN 128
#define BB 32
#define FF 64

using f32x4  = __attribute__((ext_vector_type(4))) float;
using short8 = __attribute__((ext_vector_type(8))) short;
using half8  = __attribute__((ext_vector_type(8))) _Float16;
using half4  = __attribute__((ext_vector_type(4))) _Float16;

__device__ __forceinline__ unsigned short f2bf(float x) {
    unsigned int u = __float_as_uint(x);
    u += 0x7fff + ((u >> 16) & 1);          // RNE
    return (unsigned short)(u >> 16);
}
__device__ __forceinline__ unsigned short f2bf_fast(float x) {
    return (unsigned short)((__float_as_uint(x) + 0x8000u) >> 16);
}

// -------------------- setup: bake weights + init node scalars --------------
// blocks [0,192):    w2frag / wT4 / w1f16 bake
// blocks [192,1216): s0 = embed[species] + glob @ glob_w
__global__ __launch_bounds__(256) void setup_kernel(
    const float* __restrict__ w2,     // [2][64][192]
    const float* __restrict__ ws,     // [2][64][64]
    const float* __restrict__ wv,     // [2][64][64]
    const float* __restrict__ rbf_w1, // [2][8][64]
    const float* __restrict__ rbf_b1, // [2][64]
    const int* __restrict__ species, const float* __restrict__ glob,
    const float* __restrict__ embed, const float* __restrict__ glob_w,
    short* __restrict__ w2frag,       // [2][4][3][2][64][8] = 24576 shorts
    float* __restrict__ wT4,          // [2][2][16][64][4]   = 16384 floats
    _Float16* __restrict__ w1f16,     // [2][4][64][8]       = 4096 halfs
    float* __restrict__ s)            // [B*N][64]
{
    const int blk = blockIdx.x;
    if (blk < 192) {
        const int tid = blk * 256 + threadIdx.x;
        const int NFRAG = 24576;
        if (tid < NFRAG) {
            const int e  = tid & 7;
            const int l  = (tid >> 3) & 63;
            const int ks = (tid >> 9) & 1;
            const int q  = tid >> 10;          // layer*12 + wave*3 + nt
            const int nt = q % 3;
            const int wv_ = (q / 3) & 3;
            const int layer = q / 12;
            const int col = nt * 64 + wv_ * 16 + (l & 15);
            const int hb  = ks * 32 + (l >> 4) * 8 + e;
            const float val = w2[layer * 64 * 192 + hb * 192 + col] * (1.0f / 127.0f);
            w2frag[tid] = (short)f2bf(val);
        }
        const int tid2 = tid - NFRAG;
        if (tid2 >= 0 && tid2 < 16384) {
            const int c   = tid2 & 3;
            const int g   = (tid2 >> 2) & 63;
            const int ff4 = (tid2 >> 8) & 15;
            const int m   = (tid2 >> 12) & 1;
            const int layer = tid2 >> 13;
            const float* src = (m == 0 ? ws : wv) + layer * 4096;
            wT4[tid2] = src[(ff4 * 4 + c) * 64 + g];
        }
        const int tid3 = tid - NFRAG - 16384;
        if (tid3 >= 0 && tid3 < 8192) {
            const int e  = tid3 & 7;
            const int l  = (tid3 >> 3) & 63;
            const int wv_ = (tid3 >> 9) & 3;
            const int layer = tid3 >> 11;
            const int k = (l >> 4) * 8 + e;
            const int h = wv_ * 16 + (l & 15);
            float val = 0.0f;
            if (k < 8)       val = rbf_w1[layer * 512 + k * 64 + h];
            else if (k == 8) val = rbf_b1[layer * 64 + h];
            w1f16[tid3] = (_Float16)val;
        }
    } else {
        const int node = (blk - 192) * 4 + (threadIdx.x >> 6);   // b*128 + n
        const int b = node >> 7;
        const int f = threadIdx.x & 63;
        const int sp = species[node];
        float acc = embed[sp * FF + f];
#pragma unroll
        for (int k = 0; k < 16; ++k)
            acc = fmaf(glob[b * 16 + k], glob_w[k * FF + f], acc);
        s[node * FF + f] = acc;
    }
}

// -------------------- fused message+agg+update (+readout for LAYER==1) ----
// grid 4096 (XCD-swizzled), block 256 = 4 waves.
// wave w owns channels f in [16w, 16w+16).
template<int LAYER>
__global__ __launch_bounds__(256, 4) void msg_kernel(
    const float* __restrict__ pos,     // [B][N][3]
    const float* __restrict__ s_in,    // [B][N][F]
    const float* __restrict__ v_in,    // [B][N][F][4]  (unused when LAYER==0)
    const half8* __restrict__ w1fbuf,  // [4][64] half8 (W1|b1 b-frags; layer slice)
    const short* __restrict__ w2frag,  // [4][3][2][64][8] bf16 (layer slice)
    const float* __restrict__ wT4,     // [2][16][64][4] (ws,wv; layer slice)
    const float* __restrict__ wout,    // [64]
    const float* __restrict__ scale,   // [1]
    float* __restrict__ s_out,         // LAYER==0 only
    float* __restrict__ v_out,         // LAYER==0 only, [B][N][F][4]
    float* __restrict__ out)           // LAYER==1 only
{
    __shared__ unsigned short hid_lds[NN * 64];       // 16 KB, XOR-swizzled rows
    __shared__ float4 unit_lds[NN];                   // 2 KB
    __shared__ __align__(16) char phi_pool[NN * 64];  // 8 KB: phi f16 A-tiles; agg4 aliases after A2
    float4 (*agg4)[16] = (float4(*)[16])phi_pool;

    // XCD-aware swizzle: 4 consecutive batches per XCD -> L2-resident s/v.
    const int blk = blockIdx.x;
    const int xcd = blk & 7;
    const int idx = blk >> 3;            // 0..511
    const int b = xcd * 4 + (idx >> 7);
    const int i = idx & 127;

    const int t = threadIdx.x;
    const int w = t >> 6;          // wave
    const int l = t & 63;          // lane
    const int node = b * NN + i;
    const float* pb = pos + b * NN * 3;

    // ---- B fragments (W2), pre-baked: 6 coalesced 16B loads ----
    short8 bfrag[3][2];
    {
        const short8* wf = (const short8*)w2frag;
#pragma unroll
        for (int nt = 0; nt < 3; ++nt)
#pragma unroll
            for (int ks = 0; ks < 2; ++ks)
                bfrag[nt][ks] = wf[((w * 3 + nt) * 2 + ks) * 64 + l];
    }

    // ---- phase A1: distance/unit + phi (f16, MFMA-A layout) ----
    // phi_pool row j (64B): chunks (16B, XOR-swizzled by (j&3)<<4):
    //   chunk0 = phi[0..7], chunk1 = {1.0 (bias col k=8), 0...}, chunks 2,3 = 0.
    {
        const int j = t & 127;
        const int half = t >> 7;
        const float dx = pb[i * 3 + 0] - pb[j * 3 + 0];
        const float dy = pb[i * 3 + 1] - pb[j * 3 + 1];
        const float dz = pb[i * 3 + 2] - pb[j * 3 + 2];
        const float d2 = fmaf(dx, dx, fmaf(dy, dy, fmaf(dz, dz, 1e-12f)));
        const float inv = __builtin_amdgcn_rsqf(d2);
        const float dd = d2 * inv;
        if (half == 0)
            unit_lds[j] = make_float4(dx * inv, dy * inv, dz * inv, 0.0f);
        half4 ph;
#pragma unroll
        for (int r = 0; r < 4; ++r) {
            const float td = dd - (float)(half * 4 + r) * (5.0f / 7.0f);
            ph[r] = (_Float16)__expf(td * td * -1.28f);   // 1/(2*0.625^2)
        }
        const half4 z4 = {(_Float16)0.f, (_Float16)0.f, (_Float16)0.f, (_Float16)0.f};
        const half8 z8 = {(_Float16)0.f, (_Float16)0.f, (_Float16)0.f, (_Float16)0.f,
                          (_Float16)0.f, (_Float16)0.f, (_Float16)0.f, (_Float16)0.f};
        if (j == i) ph = z4;                       // zero row i -> hid[i] = silu(0) = 0
        char* rowp = phi_pool + j * 64;
        const int swz = (j & 3) << 4;
        *(half4*)(rowp + (0 ^ swz) + half * 8) = ph;
        if (half == 0) {
            half8 bias = z8;
            bias[0] = (j == i) ? (_Float16)0.f : (_Float16)1.0f;
            *(half8*)(rowp + (16 ^ swz)) = bias;
        } else {
            *(half8*)(rowp + (32 ^ swz)) = z8;
            *(half8*)(rowp + (48 ^ swz)) = z8;
        }
    }
    __syncthreads();

    // ---- phase A2: preact = phi @ [W1;b1] via MFMA; silu -> hid_lds bf16 ---
    {
        const half8 w1f = w1fbuf[w * 64 + l];
        const int hcol2 = (w * 16 + (l & 15)) * 2;
        const int g4 = (l >> 4) * 4;
        int wo[4];
#pragma unroll
        for (int r = 0; r < 4; ++r)
            wo[r] = (g4 + r) * 128 + (hcol2 ^ (((g4 + r) & 7) << 4));
        const int rbase = (l & 15) * 64 + (((l >> 4) * 16) ^ ((l & 3) << 4));
#pragma unroll
        for (int mt = 0; mt < 8; ++mt) {
            const half8 aphi = *(const half8*)(phi_pool + mt * 1024 + rbase);
            f32x4 pre = __builtin_amdgcn_mfma_f32_16x16x32_f16(
                aphi, w1f, (f32x4){0.f, 0.f, 0.f, 0.f}, 0, 0, 0);
#pragma unroll
            for (int r = 0; r < 4; ++r) {
                const float z = pre[r];
                const float ex = __expf(-z);
                const float sv = z * __builtin_amdgcn_rcpf(1.0f + ex);
                *(unsigned short*)((char*)hid_lds + mt * 2048 + wo[r]) = f2bf_fast(sv);
            }
        }
    }
    __syncthreads();

    // ---- fused phase B+C: per 16-row j-tile, MFMA then consume ----
    const int f    = w * 16 + (l & 15);
    const int jsub = (l >> 4) * 4;
    const float* sb = s_in + b * NN * FF;
    const float4* vb4 = (LAYER > 0) ? ((const float4*)v_in) + b * NN * FF : nullptr;

    float accs = 0.f, av0 = 0.f, av1 = 0.f, av2 = 0.f;

    float sP[4]; float4 vP[4];
#pragma unroll
    for (int reg = 0; reg < 4; ++reg) {
        const int j = jsub + reg;
        sP[reg] = sb[j * FF + f];
        if (LAYER > 0) vP[reg] = vb4[j * FF + f];
    }

#pragma unroll
    for (int mt = 0; mt < 8; ++mt) {
        const int jA = mt * 16 + (l & 15);
        const int base = jA * 128;
        const int sw = (jA & 7) << 4;
        const short8 a0 = *(const short8*)((const char*)hid_lds + base + (((l >> 4) * 16 +  0) ^ sw));
        const short8 a1 = *(const short8*)((const char*)hid_lds + base + (((l >> 4) * 16 + 64) ^ sw));

        f32x4 c0 = (f32x4){0.f, 0.f, 0.f, 0.f};
        f32x4 c1 = (f32x4){0.f, 0.f, 0.f, 0.f};
        f32x4 c2 = (f32x4){0.f, 0.f, 0.f, 0.f};
        c0 = __builtin_amdgcn_mfma_f32_16x16x32_bf16(a0, bfrag[0][0], c0, 0, 0, 0);
        c0 = __builtin_amdgcn_mfma_f32_16x16x32_bf16(a1, bfrag[0][1], c0, 0, 0, 0);
        c1 = __builtin_amdgcn_mfma_f32_16x16x32_bf16(a0, bfrag[1][0], c1, 0, 0, 0);
        c1 = __builtin_amdgcn_mfma_f32_16x16x32_bf16(a1, bfrag[1][1], c1, 0, 0, 0);
        c2 = __builtin_amdgcn_mfma_f32_16x16x32_bf16(a0, bfrag[2][0], c2, 0, 0, 0);
        c2 = __builtin_amdgcn_mfma_f32_16x16x32_bf16(a1, bfrag[2][1], c2, 0, 0, 0);

        float sN[4]; float4 vN[4];
        if (mt < 7) {
#pragma unroll
            for (int reg = 0; reg < 4; ++reg) {
                const int j = (mt + 1) * 16 + jsub + reg;
                sN[reg] = sb[j * FF + f];
                if (LAYER > 0) vN[reg] = vb4[j * FF + f];
            }
        }

#pragma unroll
        for (int reg = 0; reg < 4; ++reg) {
            const int j  = mt * 16 + jsub + reg;
            const float r1 = c0[reg];
            const float r2 = c1[reg];
            const float r3 = c2[reg];
            const float sj = sP[reg];
            const float r3s = r3 * sj;
            const float4 u = unit_lds[j];
            accs = fmaf(r1, sj, accs);
            av0 = fmaf(r3s, u.x, av0);
            av1 = fmaf(r3s, u.y, av1);
            av2 = fmaf(r3s, u.z, av2);
            if (LAYER > 0) {
                av0 = fmaf(r2, vP[reg].x, av0);
                av1 = fmaf(r2, vP[reg].y, av1);
                av2 = fmaf(r2, vP[reg].z, av2);
            }
        }
#pragma unroll
        for (int reg = 0; reg < 4; ++reg) {
            sP[reg] = sN[reg];
            if (LAYER > 0) vP[reg] = vN[reg];
        }
    }

    accs += __shfl_xor(accs, 16, 64); accs += __shfl_xor(accs, 32, 64);
    av0  += __shfl_xor(av0, 16, 64);  av0  += __shfl_xor(av0, 32, 64);
    av1  += __shfl_xor(av1, 16, 64);  av1  += __shfl_xor(av1, 32, 64);
    av2  += __shfl_xor(av2, 16, 64);  av2  += __shfl_xor(av2, 32, 64);
    if (l < 16) {
        // 1/127 already folded into W2 fragments; phi_pool is dead -> agg4 alias OK
        ((float*)agg4)[0 * 64 + f] = accs;
        ((float*)agg4)[1 * 64 + f] = av0;
        ((float*)agg4)[2 * 64 + f] = av1;
        ((float*)agg4)[3 * 64 + f] = av2;
    }
    __syncthreads();

    // ---- tail: node update (+ readout for last layer), coalesced wT4 ------
    const int g = l;
    const float4* wv4 = (const float4*)wT4;
    if (LAYER == 0) {
        const int m = (w == 0) ? 0 : 1;
        const int row = (w == 0) ? 0 : w;
        float a = (w == 0) ? s_in[node * FF + g] : 0.0f;
#pragma unroll
        for (int k = 0; k < 16; ++k) {
            const float4 w4 = wv4[(m * 16 + k) * 64 + g];
            const float4 a4 = agg4[row][k];
            a = fmaf(a4.x, w4.x, a); a = fmaf(a4.y, w4.y, a);
            a = fmaf(a4.z, w4.z, a); a = fmaf(a4.w, w4.w, a);
        }
        if (w == 0) s_out[node * FF + g] = a;
        else        v_out[(node * FF + g) * 4 + (w - 1)] = a;
    } else {
        if (w > 0) {
            const int d = w - 1;
            float a = v_in[(node * FF + g) * 4 + d];
#pragma unroll
            for (int k = 0; k < 16; ++k) {
                const float4 w4 = wv4[(16 + k) * 64 + g];
                const float4 a4 = agg4[w][k];
                a = fmaf(a4.x, w4.x, a); a = fmaf(a4.y, w4.y, a);
                a = fmaf(a4.z, w4.z, a); a = fmaf(a4.w, w4.w, a);
            }
            float p = a * wout[g];
#pragma unroll
            for (int off = 1; off < 64; off <<= 1)
                p += __shfl_xor(p, off, 64);
            if (l == 0)
                out[node * 3 + d] = (p - pos[node * 3 + d]) * scale[0];
        }
    }
}

extern "C" void kernel_launch(void* const* d_in, const int* in_sizes, int n_in,
                              void* d_out, int out_size, void* d_ws, size_t ws_size,
                              hipStream_t stream) {
    const float* pos     = (const float*)d_in[0];
    const int*   species = (const int*)  d_in[1];
    const float* glob    = (const float*)d_in[2];
    const float* embed   = (const float*)d_in[3];
    const float* glob_w  = (const float*)d_in[4];
    const float* rbf_w1  = (const float*)d_in[5];   // [2][8][64]
    const float* rbf_b1  = (const float*)d_in[6];   // [2][64]
    const float* rbf_w2  = (const float*)d_in[7];   // [2][64][192]
    const float* ws      = (const float*)d_in[8];   // [2][64][64]
    const float* wv      = (const float*)d_in[9];   // [2][64][64]
    const float* wout    = (const float*)d_in[10];  // [64]
    const float* scale   = (const float*)d_in[11];  // [1]

    float* wsf = (float*)d_ws;
    float* s0     = wsf;                       // 262144 floats
    float* s1     = wsf + 262144;              // 262144
    float* v1     = wsf + 524288;              // 1048576
    short* w2frag = (short*)(wsf + 1572864);   // 24576 shorts (12288 floats)
    float* wT4    = wsf + 1585152;             // 16384 floats
    _Float16* w1f16 = (_Float16*)(wsf + 1601536); // 8192 halfs (4096 floats)
    float* outp = (float*)d_out;

    setup_kernel<<<dim3(192 + BB * NN / 4), 256, 0, stream>>>(
        rbf_w2, ws, wv, rbf_w1, rbf_b1, species, glob, embed, glob_w,
        w2frag, wT4, w1f16, s0);

    msg_kernel<0><<<dim3(NN * BB), 256, 0, stream>>>(
        pos, s0, nullptr,
        (const half8*)w1f16, w2frag, wT4, wout, scale,
        s1, v1, nullptr);

    msg_kernel<1><<<dim3(NN * BB), 256, 0, stream>>>(
        pos, s1, v1,
        (const half8*)(w1f16 + 2048), w2frag + 12288, wT4 + 8192, wout, scale,
        nullptr, nullptr, outp);
}

// Round 10
// 82.814 us; speedup vs baseline: 3.8211x; 1.0012x over previous
//
#include <hip/hip_runtime.h>
#include <hip/hip_bf16.h>

// MACE-like GNN on MI355X — MFMA for BOTH GEMMs.
// B=32, N=128, F=64, N_RBF=8, H_R=64, L=2.
// Round 10: A2 via SWAPPED mfma_f32_16x16x16f16 (D[h,j]) -> packed b64 hid
// writes (kills the 917K bank conflicts), K=16 phi tiles (half the LDS).

#define NN 128
#define BB 32
#define FF 64

using f32x4  = __attribute__((ext_vector_type(4))) float;
using short8 = __attribute__((ext_vector_type(8))) short;
using half4  = __attribute__((ext_vector_type(4))) _Float16;

__device__ __forceinline__ unsigned short f2bf(float x) {
    unsigned int u = __float_as_uint(x);
    u += 0x7fff + ((u >> 16) & 1);          // RNE
    return (unsigned short)(u >> 16);
}
__device__ __forceinline__ unsigned int f2bf_fast32(float x) {
    return (__float_as_uint(x) + 0x8000u) >> 16;
}

// -------------------- setup: bake weights + init node scalars --------------
// blocks [0,192):    w2frag / wT4 / w1A bake
// blocks [192,1216): s0 = embed[species] + glob @ glob_w
__global__ __launch_bounds__(256) void setup_kernel(
    const float* __restrict__ w2,     // [2][64][192]
    const float* __restrict__ ws,     // [2][64][64]
    const float* __restrict__ wv,     // [2][64][64]
    const float* __restrict__ rbf_w1, // [2][8][64]
    const float* __restrict__ rbf_b1, // [2][64]
    const int* __restrict__ species, const float* __restrict__ glob,
    const float* __restrict__ embed, const float* __restrict__ glob_w,
    short* __restrict__ w2frag,       // [2][4][3][2][64][8] = 24576 shorts
    float* __restrict__ wT4,          // [2][2][16][64][4]   = 16384 floats
    _Float16* __restrict__ w1A,       // [2][4][64][4]       = 2048 halfs
    float* __restrict__ s)            // [B*N][64]
{
    const int blk = blockIdx.x;
    if (blk < 192) {
        const int tid = blk * 256 + threadIdx.x;
        const int NFRAG = 24576;
        if (tid < NFRAG) {
            const int e  = tid & 7;
            const int l  = (tid >> 3) & 63;
            const int ks = (tid >> 9) & 1;
            const int q  = tid >> 10;          // layer*12 + wave*3 + nt
            const int nt = q % 3;
            const int wv_ = (q / 3) & 3;
            const int layer = q / 12;
            const int col = nt * 64 + wv_ * 16 + (l & 15);
            const int hb  = ks * 32 + (l >> 4) * 8 + e;
            const float val = w2[layer * 64 * 192 + hb * 192 + col] * (1.0f / 127.0f);
            w2frag[tid] = (short)f2bf(val);
        }
        const int tid2 = tid - NFRAG;
        if (tid2 >= 0 && tid2 < 16384) {
            const int c   = tid2 & 3;
            const int g   = (tid2 >> 2) & 63;
            const int ff4 = (tid2 >> 8) & 15;
            const int m   = (tid2 >> 12) & 1;
            const int layer = tid2 >> 13;
            const float* src = (m == 0 ? ws : wv) + layer * 4096;
            wT4[tid2] = src[(ff4 * 4 + c) * 64 + g];
        }
        const int tid3 = tid - NFRAG - 16384;
        if (tid3 >= 0 && tid3 < 2048) {
            // A-frag for 16x16x16: lane l holds A[row=l&15][k=(l>>4)*4+e]
            // A = [W1 ; b1]^T : A[h][k] = W1[k][h] (k<8), b1[h] (k==8), 0 else
            const int e  = tid3 & 3;
            const int l  = (tid3 >> 2) & 63;
            const int wv_ = (tid3 >> 8) & 3;
            const int layer = tid3 >> 10;
            const int k = (l >> 4) * 4 + e;
            const int h = wv_ * 16 + (l & 15);
            float val = 0.0f;
            if (k < 8)       val = rbf_w1[layer * 512 + k * 64 + h];
            else if (k == 8) val = rbf_b1[layer * 64 + h];
            w1A[tid3] = (_Float16)val;
        }
    } else {
        const int node = (blk - 192) * 4 + (threadIdx.x >> 6);   // b*128 + n
        const int b = node >> 7;
        const int f = threadIdx.x & 63;
        const int sp = species[node];
        float acc = embed[sp * FF + f];
#pragma unroll
        for (int k = 0; k < 16; ++k)
            acc = fmaf(glob[b * 16 + k], glob_w[k * FF + f], acc);
        s[node * FF + f] = acc;
    }
}

// -------------------- fused message+agg+update (+readout for LAYER==1) ----
// grid 4096 (XCD-swizzled), block 256 = 4 waves.
// wave w owns channels f in [16w, 16w+16).
template<int LAYER>
__global__ __launch_bounds__(256, 4) void msg_kernel(
    const float* __restrict__ pos,     // [B][N][3]
    const float* __restrict__ s_in,    // [B][N][F]
    const float* __restrict__ v_in,    // [B][N][F][4]  (unused when LAYER==0)
    const half4* __restrict__ w1Abuf,  // [4][64] half4 (layer slice)
    const short* __restrict__ w2frag,  // [4][3][2][64][8] bf16 (layer slice)
    const float* __restrict__ wT4,     // [2][16][64][4] (ws,wv; layer slice)
    const float* __restrict__ wout,    // [64]
    const float* __restrict__ scale,   // [1]
    float* __restrict__ s_out,         // LAYER==0 only
    float* __restrict__ v_out,         // LAYER==0 only, [B][N][F][4]
    float* __restrict__ out)           // LAYER==1 only
{
    __shared__ unsigned short hid_lds[NN * 64];       // 16 KB, XOR-swizzled rows
    __shared__ float4 unit_lds[NN];                   // 2 KB
    __shared__ __align__(16) char phi_pool[NN * 32];  // 4 KB; agg4 aliases after A2
    float4 (*agg4)[16] = (float4(*)[16])phi_pool;

    // XCD-aware swizzle: 4 consecutive batches per XCD -> L2-resident s/v.
    const int blk = blockIdx.x;
    const int xcd = blk & 7;
    const int idx = blk >> 3;            // 0..511
    const int b = xcd * 4 + (idx >> 7);
    const int i = idx & 127;

    const int t = threadIdx.x;
    const int w = t >> 6;          // wave
    const int l = t & 63;          // lane
    const int node = b * NN + i;
    const float* pb = pos + b * NN * 3;

    // ---- B fragments (W2), pre-baked: 6 coalesced 16B loads ----
    short8 bfrag[3][2];
    {
        const short8* wf = (const short8*)w2frag;
#pragma unroll
        for (int nt = 0; nt < 3; ++nt)
#pragma unroll
            for (int ks = 0; ks < 2; ++ks)
                bfrag[nt][ks] = wf[((w * 3 + nt) * 2 + ks) * 64 + l];
    }

    // ---- phase A1: distance/unit + phi (f16 rows [128][16], K=16 layout) ---
    // row j (32B): halfs k=0..15 = [phi0..7, bias, 0,0,0,0,0,0,0],
    // 8B chunks XOR-swizzled by ((j>>2)&3)<<3.
    {
        const int j = t & 127;
        const int half = t >> 7;
        const float dx = pb[i * 3 + 0] - pb[j * 3 + 0];
        const float dy = pb[i * 3 + 1] - pb[j * 3 + 1];
        const float dz = pb[i * 3 + 2] - pb[j * 3 + 2];
        const float d2 = fmaf(dx, dx, fmaf(dy, dy, fmaf(dz, dz, 1e-12f)));
        const float inv = __builtin_amdgcn_rsqf(d2);
        const float dd = d2 * inv;
        if (half == 0)
            unit_lds[j] = make_float4(dx * inv, dy * inv, dz * inv, 0.0f);
        const _Float16 zf = (_Float16)0.f;
        half4 ph;
#pragma unroll
        for (int r = 0; r < 4; ++r) {
            const float td = dd - (float)(half * 4 + r) * (5.0f / 7.0f);
            ph[r] = (_Float16)__expf(td * td * -1.28f);   // 1/(2*0.625^2)
        }
        if (j == i) ph = (half4){zf, zf, zf, zf};
        char* rowp = phi_pool + j * 32;
        const int swz = ((j >> 2) & 3) << 3;
        *(half4*)(rowp + ((half * 8) ^ swz)) = ph;
        if (half == 0) {
            half4 bias = {(j == i) ? zf : (_Float16)1.0f, zf, zf, zf};
            *(half4*)(rowp + (16 ^ swz)) = bias;          // k=8..11
        } else {
            *(half4*)(rowp + (24 ^ swz)) = (half4){zf, zf, zf, zf}; // k=12..15
        }
    }
    __syncthreads();

    // ---- phase A2: pre[h,j] = mfma(W1^T, phi^T); silu -> hid_lds (b64) ----
    {
        const half4 w1a = w1Abuf[w * 64 + l];
        const int jcol = l & 15;
        const int chunk = (l >> 4) * 8;
        const int hbyte = w * 32 + (l >> 4) * 8;   // h = w*16 + (l>>4)*4 + reg
#pragma unroll
        for (int mt = 0; mt < 8; ++mt) {
            const int j = mt * 16 + jcol;
            const half4 bphi = *(const half4*)(
                phi_pool + j * 32 + (chunk ^ (((j >> 2) & 3) << 3)));
            f32x4 pre = __builtin_amdgcn_mfma_f32_16x16x16f16(
                w1a, bphi, (f32x4){0.f, 0.f, 0.f, 0.f}, 0, 0, 0);
            unsigned int pk[2];
#pragma unroll
            for (int p = 0; p < 2; ++p) {
                float sv[2];
#pragma unroll
                for (int q = 0; q < 2; ++q) {
                    const float z = pre[p * 2 + q];
                    const float ex = __expf(-z);
                    sv[q] = z * __builtin_amdgcn_rcpf(1.0f + ex);
                }
                pk[p] = f2bf_fast32(sv[0]) | (f2bf_fast32(sv[1]) << 16);
            }
            const int byte = j * 128 + (hbyte ^ ((j & 7) << 4));
            *(uint2*)((char*)hid_lds + byte) = make_uint2(pk[0], pk[1]);
        }
    }
    __syncthreads();

    // ---- fused phase B+C: per 16-row j-tile, MFMA then consume ----
    const int f    = w * 16 + (l & 15);
    const int jsub = (l >> 4) * 4;
    const float* sb = s_in + b * NN * FF;
    const float4* vb4 = (LAYER > 0) ? ((const float4*)v_in) + b * NN * FF : nullptr;

    float accs = 0.f, av0 = 0.f, av1 = 0.f, av2 = 0.f;

    float sP[4]; float4 vP[4];
#pragma unroll
    for (int reg = 0; reg < 4; ++reg) {
        const int j = jsub + reg;
        sP[reg] = sb[j * FF + f];
        if (LAYER > 0) vP[reg] = vb4[j * FF + f];
    }

#pragma unroll
    for (int mt = 0; mt < 8; ++mt) {
        const int jA = mt * 16 + (l & 15);
        const int base = jA * 128;
        const int sw = (jA & 7) << 4;
        const short8 a0 = *(const short8*)((const char*)hid_lds + base + (((l >> 4) * 16 +  0) ^ sw));
        const short8 a1 = *(const short8*)((const char*)hid_lds + base + (((l >> 4) * 16 + 64) ^ sw));

        f32x4 c0 = (f32x4){0.f, 0.f, 0.f, 0.f};
        f32x4 c1 = (f32x4){0.f, 0.f, 0.f, 0.f};
        f32x4 c2 = (f32x4){0.f, 0.f, 0.f, 0.f};
        c0 = __builtin_amdgcn_mfma_f32_16x16x32_bf16(a0, bfrag[0][0], c0, 0, 0, 0);
        c0 = __builtin_amdgcn_mfma_f32_16x16x32_bf16(a1, bfrag[0][1], c0, 0, 0, 0);
        c1 = __builtin_amdgcn_mfma_f32_16x16x32_bf16(a0, bfrag[1][0], c1, 0, 0, 0);
        c1 = __builtin_amdgcn_mfma_f32_16x16x32_bf16(a1, bfrag[1][1], c1, 0, 0, 0);
        c2 = __builtin_amdgcn_mfma_f32_16x16x32_bf16(a0, bfrag[2][0], c2, 0, 0, 0);
        c2 = __builtin_amdgcn_mfma_f32_16x16x32_bf16(a1, bfrag[2][1], c2, 0, 0, 0);

        float sN[4]; float4 vN[4];
        if (mt < 7) {
#pragma unroll
            for (int reg = 0; reg < 4; ++reg) {
                const int j = (mt + 1) * 16 + jsub + reg;
                sN[reg] = sb[j * FF + f];
                if (LAYER > 0) vN[reg] = vb4[j * FF + f];
            }
        }

#pragma unroll
        for (int reg = 0; reg < 4; ++reg) {
            const int j  = mt * 16 + jsub + reg;
            const float r1 = c0[reg];
            const float r2 = c1[reg];
            const float r3 = c2[reg];
            const float sj = sP[reg];
            const float r3s = r3 * sj;
            const float4 u = unit_lds[j];
            accs = fmaf(r1, sj, accs);
            av0 = fmaf(r3s, u.x, av0);
            av1 = fmaf(r3s, u.y, av1);
            av2 = fmaf(r3s, u.z, av2);
            if (LAYER > 0) {
                av0 = fmaf(r2, vP[reg].x, av0);
                av1 = fmaf(r2, vP[reg].y, av1);
                av2 = fmaf(r2, vP[reg].z, av2);
            }
        }
#pragma unroll
        for (int reg = 0; reg < 4; ++reg) {
            sP[reg] = sN[reg];
            if (LAYER > 0) vP[reg] = vN[reg];
        }
    }

    accs += __shfl_xor(accs, 16, 64); accs += __shfl_xor(accs, 32, 64);
    av0  += __shfl_xor(av0, 16, 64);  av0  += __shfl_xor(av0, 32, 64);
    av1  += __shfl_xor(av1, 16, 64);  av1  += __shfl_xor(av1, 32, 64);
    av2  += __shfl_xor(av2, 16, 64);  av2  += __shfl_xor(av2, 32, 64);
    if (l < 16) {
        // 1/127 already folded into W2 fragments; phi_pool dead -> agg4 alias OK
        ((float*)agg4)[0 * 64 + f] = accs;
        ((float*)agg4)[1 * 64 + f] = av0;
        ((float*)agg4)[2 * 64 + f] = av1;
        ((float*)agg4)[3 * 64 + f] = av2;
    }
    __syncthreads();

    // ---- tail: node update (+ readout for last layer), coalesced wT4 ------
    const int g = l;
    const float4* wv4 = (const float4*)wT4;
    if (LAYER == 0) {
        const int m = (w == 0) ? 0 : 1;
        const int row = (w == 0) ? 0 : w;
        float a = (w == 0) ? s_in[node * FF + g] : 0.0f;
#pragma unroll
        for (int k = 0; k < 16; ++k) {
            const float4 w4 = wv4[(m * 16 + k) * 64 + g];
            const float4 a4 = agg4[row][k];
            a = fmaf(a4.x, w4.x, a); a = fmaf(a4.y, w4.y, a);
            a = fmaf(a4.z, w4.z, a); a = fmaf(a4.w, w4.w, a);
        }
        if (w == 0) s_out[node * FF + g] = a;
        else        v_out[(node * FF + g) * 4 + (w - 1)] = a;
    } else {
        if (w > 0) {
            const int d = w - 1;
            float a = v_in[(node * FF + g) * 4 + d];
#pragma unroll
            for (int k = 0; k < 16; ++k) {
                const float4 w4 = wv4[(16 + k) * 64 + g];
                const float4 a4 = agg4[w][k];
                a = fmaf(a4.x, w4.x, a); a = fmaf(a4.y, w4.y, a);
                a = fmaf(a4.z, w4.z, a); a = fmaf(a4.w, w4.w, a);
            }
            float p = a * wout[g];
#pragma unroll
            for (int off = 1; off < 64; off <<= 1)
                p += __shfl_xor(p, off, 64);
            if (l == 0)
                out[node * 3 + d] = (p - pos[node * 3 + d]) * scale[0];
        }
    }
}

extern "C" void kernel_launch(void* const* d_in, const int* in_sizes, int n_in,
                              void* d_out, int out_size, void* d_ws, size_t ws_size,
                              hipStream_t stream) {
    const float* pos     = (const float*)d_in[0];
    const int*   species = (const int*)  d_in[1];
    const float* glob    = (const float*)d_in[2];
    const float* embed   = (const float*)d_in[3];
    const float* glob_w  = (const float*)d_in[4];
    const float* rbf_w1  = (const float*)d_in[5];   // [2][8][64]
    const float* rbf_b1  = (const float*)d_in[6];   // [2][64]
    const float* rbf_w2  = (const float*)d_in[7];   // [2][64][192]
    const float* ws      = (const float*)d_in[8];   // [2][64][64]
    const float* wv      = (const float*)d_in[9];   // [2][64][64]
    const float* wout    = (const float*)d_in[10];  // [64]
    const float* scale   = (const float*)d_in[11];  // [1]

    float* wsf = (float*)d_ws;
    float* s0     = wsf;                       // 262144 floats
    float* s1     = wsf + 262144;              // 262144
    float* v1     = wsf + 524288;              // 1048576
    short* w2frag = (short*)(wsf + 1572864);   // 24576 shorts (12288 floats)
    float* wT4    = wsf + 1585152;             // 16384 floats
    _Float16* w1A = (_Float16*)(wsf + 1601536); // 2048 halfs (1024 floats)
    float* outp = (float*)d_out;

    setup_kernel<<<dim3(192 + BB * NN / 4), 256, 0, stream>>>(
        rbf_w2, ws, wv, rbf_w1, rbf_b1, species, glob, embed, glob_w,
        w2frag, wT4, w1A, s0);

    msg_kernel<0><<<dim3(NN * BB), 256, 0, stream>>>(
        pos, s0, nullptr,
        (const half4*)w1A, w2frag, wT4, wout, scale,
        s1, v1, nullptr);

    msg_kernel<1><<<dim3(NN * BB), 256, 0, stream>>>(
        pos, s1, v1,
        (const half4*)(w1A + 1024), w2frag + 12288, wT4 + 8192, wout, scale,
        nullptr, nullptr, outp);
}